// Round 5
// baseline (423.497 us; speedup 1.0000x reference)
//
#include <hip/hip_runtime.h>

constexpr int Uc = 100000;
constexpr int Ic = 50000;
constexpr int Nc = 150000;   // U + I
constexpr int Ec = 1000000;
constexpr int Bc = 16384;
constexpr int NBS = (Nc + 1023) / 1024;  // scan chunks = 147

// ---------------- kernels ----------------

// deg count over undirected edges + (block 0) Fp[d] = F[d,:] @ pw
__global__ void k_deg2_fproj(const int* __restrict__ un, const int* __restrict__ in_,
                             unsigned* __restrict__ deg,
                             const float* __restrict__ F, const float* __restrict__ pw,
                             float* __restrict__ Fp) {
    if (blockIdx.x == 0 && threadIdx.x < 64) {
        int d = threadIdx.x;
        float s = 0.f;
#pragma unroll
        for (int j = 0; j < 64; ++j) s += F[d * 64 + j] * pw[j];
        Fp[d] = s;
    }
    int e = blockIdx.x * blockDim.x + threadIdx.x;
    if (e < Ec) {
        atomicAdd(&deg[un[e]], 1u);
        atomicAdd(&deg[in_[e]], 1u);
    }
}

// --- scan phase 1: per-1024-chunk exclusive scan of deg; also writes dinv ---
__global__ void k_scan1(const unsigned* __restrict__ deg, int* __restrict__ rowptr,
                        int* __restrict__ bsums, float* __restrict__ dinv) {
    __shared__ int sh[256];
    int tid = threadIdx.x, bid = blockIdx.x;
    int base = bid * 1024 + tid * 4;
    int v0 = (base + 0 < Nc) ? (int)deg[base + 0] : 0;
    int v1 = (base + 1 < Nc) ? (int)deg[base + 1] : 0;
    int v2 = (base + 2 < Nc) ? (int)deg[base + 2] : 0;
    int v3 = (base + 3 < Nc) ? (int)deg[base + 3] : 0;
    if (base + 0 < Nc) dinv[base + 0] = v0 ? rsqrtf((float)v0) : 0.f;
    if (base + 1 < Nc) dinv[base + 1] = v1 ? rsqrtf((float)v1) : 0.f;
    if (base + 2 < Nc) dinv[base + 2] = v2 ? rsqrtf((float)v2) : 0.f;
    if (base + 3 < Nc) dinv[base + 3] = v3 ? rsqrtf((float)v3) : 0.f;
    int s = v0 + v1 + v2 + v3;
    sh[tid] = s;
    __syncthreads();
    for (int off = 1; off < 256; off <<= 1) {
        int t = (tid >= off) ? sh[tid - off] : 0;
        __syncthreads();
        sh[tid] += t;
        __syncthreads();
    }
    int excl = sh[tid] - s;
    if (tid == 255) bsums[bid] = sh[255];
    if (base + 0 < Nc) rowptr[base + 0] = excl;
    if (base + 1 < Nc) rowptr[base + 1] = excl + v0;
    if (base + 2 < Nc) rowptr[base + 2] = excl + v0 + v1;
    if (base + 3 < Nc) rowptr[base + 3] = excl + v0 + v1 + v2;
}

// scan of bsums folded in (each block redundantly scans 147 sums in LDS)
__global__ void k_scan3(int* __restrict__ rowptr, const int* __restrict__ bsums,
                        int* __restrict__ cursor) {
    __shared__ int sh[256];
    int tid = threadIdx.x;
    int v = (tid < NBS) ? bsums[tid] : 0;
    sh[tid] = v;
    __syncthreads();
    for (int off = 1; off < 256; off <<= 1) {
        int t = (tid >= off) ? sh[tid - off] : 0;
        __syncthreads();
        sh[tid] += t;
        __syncthreads();
    }
    int excl = sh[tid] - v;
    __syncthreads();
    sh[tid] = excl;
    __syncthreads();
    int i = blockIdx.x * blockDim.x + threadIdx.x;
    if (i < Nc) {
        int r = rowptr[i] + sh[i >> 10];
        rowptr[i] = r;
        cursor[i] = r;
    }
    if (i == 0) rowptr[Nc] = 2 * Ec;
}

// fused: edge-weight projection + CSR scatter (both directions, same coef)
__global__ void k_build(const int* __restrict__ un, const int* __restrict__ in_,
                        const float* __restrict__ ef, const float* __restrict__ Fp,
                        const float* __restrict__ pb, const float* __restrict__ dinv,
                        int* __restrict__ cursor, int2* __restrict__ csr) {
    int t = blockIdx.x * blockDim.x + threadIdx.x;
    int e = t >> 4, l = t & 15;
    if (e >= Ec) return;
    float4 f = reinterpret_cast<const float4*>(ef)[(size_t)e * 16 + l];
    float4 w = reinterpret_cast<const float4*>(Fp)[l];
    float s = f.x * w.x + f.y * w.y + f.z * w.z + f.w * w.w;
    s += __shfl_xor(s, 8, 16);
    s += __shfl_xor(s, 4, 16);
    s += __shfl_xor(s, 2, 16);
    s += __shfl_xor(s, 1, 16);
    if (l == 0 || l == 8) {
        int uu = un[e], ii = in_[e];
        float c = dinv[uu] * dinv[ii] * (s + pb[0]);
        if (l == 0) {
            int pos = atomicAdd(&cursor[ii], 1);
            csr[pos] = make_int2(uu, __float_as_int(c));
        } else {
            int pos = atomicAdd(&cursor[uu], 1);
            csr[pos] = make_int2(ii, __float_as_int(c));
        }
    }
}

// gather propagation, 8x ILP, nontemporal csr stream.
// SPLIT=1: layer-1, sources come straight from Gu/Gi (bipartite).
template <int SPLIT>
__global__ void k_gprop(const int* __restrict__ rowptr, const long long* __restrict__ csr,
                        const float* __restrict__ xGu, const float* __restrict__ xGi,
                        float* __restrict__ xn) {
    int t = blockIdx.x * blockDim.x + threadIdx.x;
    int n = t >> 4, l = t & 15;
    if (n >= Nc) return;
    int e0 = rowptr[n], e1 = rowptr[n + 1];
    const float4* xs;
    int off = 0;
    if (SPLIT) {
        if (n < Uc) { xs = reinterpret_cast<const float4*>(xGi); off = Uc * 16; }
        else        { xs = reinterpret_cast<const float4*>(xGu); }
    } else {
        xs = reinterpret_cast<const float4*>(xGu);
    }
    float4 acc = make_float4(0.f, 0.f, 0.f, 0.f);
    int e = e0;
    for (; e + 8 <= e1; e += 8) {
        long long q0 = __builtin_nontemporal_load(csr + e + 0);
        long long q1 = __builtin_nontemporal_load(csr + e + 1);
        long long q2 = __builtin_nontemporal_load(csr + e + 2);
        long long q3 = __builtin_nontemporal_load(csr + e + 3);
        long long q4 = __builtin_nontemporal_load(csr + e + 4);
        long long q5 = __builtin_nontemporal_load(csr + e + 5);
        long long q6 = __builtin_nontemporal_load(csr + e + 6);
        long long q7 = __builtin_nontemporal_load(csr + e + 7);
        float4 v0 = xs[(int)q0 * 16 - off + l];
        float4 v1 = xs[(int)q1 * 16 - off + l];
        float4 v2 = xs[(int)q2 * 16 - off + l];
        float4 v3 = xs[(int)q3 * 16 - off + l];
        float4 v4 = xs[(int)q4 * 16 - off + l];
        float4 v5 = xs[(int)q5 * 16 - off + l];
        float4 v6 = xs[(int)q6 * 16 - off + l];
        float4 v7 = xs[(int)q7 * 16 - off + l];
        float c0 = __int_as_float((int)(q0 >> 32)), c1 = __int_as_float((int)(q1 >> 32));
        float c2 = __int_as_float((int)(q2 >> 32)), c3 = __int_as_float((int)(q3 >> 32));
        float c4 = __int_as_float((int)(q4 >> 32)), c5 = __int_as_float((int)(q5 >> 32));
        float c6 = __int_as_float((int)(q6 >> 32)), c7 = __int_as_float((int)(q7 >> 32));
        acc.x += c0 * v0.x + c1 * v1.x + c2 * v2.x + c3 * v3.x
               + c4 * v4.x + c5 * v5.x + c6 * v6.x + c7 * v7.x;
        acc.y += c0 * v0.y + c1 * v1.y + c2 * v2.y + c3 * v3.y
               + c4 * v4.y + c5 * v5.y + c6 * v6.y + c7 * v7.y;
        acc.z += c0 * v0.z + c1 * v1.z + c2 * v2.z + c3 * v3.z
               + c4 * v4.z + c5 * v5.z + c6 * v6.z + c7 * v7.z;
        acc.w += c0 * v0.w + c1 * v1.w + c2 * v2.w + c3 * v3.w
               + c4 * v4.w + c5 * v5.w + c6 * v6.w + c7 * v7.w;
    }
    for (; e < e1; ++e) {
        long long q = __builtin_nontemporal_load(csr + e);
        float c = __int_as_float((int)(q >> 32));
        float4 v = xs[(int)q * 16 - off + l];
        acc.x += c * v.x; acc.y += c * v.y; acc.z += c * v.z; acc.w += c * v.w;
    }
    reinterpret_cast<float4*>(xn)[n * 16 + l] = acc;
}

// fused batch-side: acc = x0 + a1 x1 + a2 x2 + a3 (A x2), then dot.
// One 64-lane wave per (user,item) pair; lane = feature dim.
__global__ void k_final(const float* __restrict__ Gu, const float* __restrict__ Gi,
                        const float* __restrict__ x1, const float* __restrict__ x2,
                        const int* __restrict__ rowptr, const long long* __restrict__ csr,
                        const int* __restrict__ users, const int* __restrict__ items,
                        float* __restrict__ out) {
    int wid = (blockIdx.x * blockDim.x + threadIdx.x) >> 6;
    int d = threadIdx.x & 63;
    if (wid >= Bc) return;
    int un = users[wid];
    int in_ = Uc + items[wid];

    float acc2[2];
#pragma unroll
    for (int side = 0; side < 2; ++side) {
        int n = side ? in_ : un;
        float base = side ? Gi[(size_t)(n - Uc) * 64 + d] : Gu[(size_t)n * 64 + d];
        float a = base + 0.5f * x1[(size_t)n * 64 + d] + (1.f / 3.f) * x2[(size_t)n * 64 + d];
        float su = 0.f;
        int e0 = rowptr[n], e1 = rowptr[n + 1];
        int e = e0;
        for (; e + 8 <= e1; e += 8) {
            long long q0 = __builtin_nontemporal_load(csr + e + 0);
            long long q1 = __builtin_nontemporal_load(csr + e + 1);
            long long q2 = __builtin_nontemporal_load(csr + e + 2);
            long long q3 = __builtin_nontemporal_load(csr + e + 3);
            long long q4 = __builtin_nontemporal_load(csr + e + 4);
            long long q5 = __builtin_nontemporal_load(csr + e + 5);
            long long q6 = __builtin_nontemporal_load(csr + e + 6);
            long long q7 = __builtin_nontemporal_load(csr + e + 7);
            su += __int_as_float((int)(q0 >> 32)) * x2[(size_t)(int)q0 * 64 + d]
                + __int_as_float((int)(q1 >> 32)) * x2[(size_t)(int)q1 * 64 + d]
                + __int_as_float((int)(q2 >> 32)) * x2[(size_t)(int)q2 * 64 + d]
                + __int_as_float((int)(q3 >> 32)) * x2[(size_t)(int)q3 * 64 + d]
                + __int_as_float((int)(q4 >> 32)) * x2[(size_t)(int)q4 * 64 + d]
                + __int_as_float((int)(q5 >> 32)) * x2[(size_t)(int)q5 * 64 + d]
                + __int_as_float((int)(q6 >> 32)) * x2[(size_t)(int)q6 * 64 + d]
                + __int_as_float((int)(q7 >> 32)) * x2[(size_t)(int)q7 * 64 + d];
        }
        for (; e < e1; ++e) {
            long long q = __builtin_nontemporal_load(csr + e);
            su += __int_as_float((int)(q >> 32)) * x2[(size_t)(int)q * 64 + d];
        }
        acc2[side] = a + 0.25f * su;
    }

    float p = acc2[0] * acc2[1];
#pragma unroll
    for (int o = 32; o > 0; o >>= 1) p += __shfl_xor(p, o, 64);
    if (d == 0) out[wid] = p;
}

// ---------------- launch ----------------

extern "C" void kernel_launch(void* const* d_in, const int* in_sizes, int n_in,
                              void* d_out, int out_size, void* d_ws, size_t ws_size,
                              hipStream_t stream) {
    const float* Gu = (const float*)d_in[0];
    const float* Gi = (const float*)d_in[1];
    const float* F  = (const float*)d_in[2];
    const float* pw = (const float*)d_in[3];
    const float* pb = (const float*)d_in[4];
    const float* ef = (const float*)d_in[5];
    const int*   ei = (const int*)d_in[6];   // [2, 2E]
    const int* users = (const int*)d_in[7];
    const int* items = (const int*)d_in[8];
    float* out = (float*)d_out;

    float* ws = (float*)d_ws;
    float*    Fp     = ws;                          // 64
    float*    dinv   = Fp + 64;                     // N
    unsigned* deg    = (unsigned*)(dinv + Nc);      // N
    int*      rowptr = (int*)(deg + Nc);            // N+16
    int*      cursor = rowptr + (Nc + 16);          // N
    int*      bsums  = cursor + Nc;                 // 256
    int2*     csr    = (int2*)(bsums + 256);        // 2E int2
    float*    xa     = (float*)(csr + 2 * Ec);      // N*64
    float*    xb     = xa + (size_t)Nc * 64;        // N*64

    const int* un  = ei;            // user ids (first half of row 0)
    const int* in_ = ei + 2 * Ec;   // item node ids >= U (first half of row 1)

    hipMemsetAsync(deg, 0, Nc * sizeof(unsigned), stream);
    k_deg2_fproj<<<(Ec + 255) / 256, 256, 0, stream>>>(un, in_, deg, F, pw, Fp);
    k_scan1<<<NBS, 256, 0, stream>>>(deg, rowptr, bsums, dinv);
    k_scan3<<<(Nc + 255) / 256, 256, 0, stream>>>(rowptr, bsums, cursor);
    k_build<<<(Ec * 16) / 256, 256, 0, stream>>>(un, in_, ef, Fp, pb, dinv, cursor, csr);

    // layer 1: inputs -> xa ; layer 2: xa -> xb  (128-thread blocks: less tail imbalance)
    k_gprop<1><<<(Nc * 16 + 127) / 128, 128, 0, stream>>>(rowptr, (const long long*)csr, Gu, Gi, xa);
    k_gprop<0><<<(Nc * 16 + 127) / 128, 128, 0, stream>>>(rowptr, (const long long*)csr, xa, nullptr, xb);

    // fused: alpha-weighted batch accumulation + layer-3 on the fly + dot
    k_final<<<(Bc * 64) / 256, 256, 0, stream>>>(Gu, Gi, xa, xb, rowptr, (const long long*)csr, users, items, out);
}

// Round 6
// 397.158 us; speedup vs baseline: 1.0663x; 1.0663x over previous
//
#include <hip/hip_runtime.h>

constexpr int Uc = 100000;
constexpr int Ic = 50000;
constexpr int Nc = 150000;   // U + I
constexpr int Ec = 1000000;
constexpr int Bc = 16384;
constexpr int NBS = (Nc + 1023) / 1024;  // scan chunks = 147

// ---------------- kernels ----------------

// zero deg (Nc uints = 37500 uint4) — replaces pathological rocclr fill
__global__ void k_zero(uint4* __restrict__ deg4) {
    int i = blockIdx.x * blockDim.x + threadIdx.x;
    if (i < Nc / 4) deg4[i] = make_uint4(0u, 0u, 0u, 0u);
}

// deg count over undirected edges + (block 0) Fp[d] = F[d,:] @ pw
__global__ void k_deg2_fproj(const int* __restrict__ un, const int* __restrict__ in_,
                             unsigned* __restrict__ deg,
                             const float* __restrict__ F, const float* __restrict__ pw,
                             float* __restrict__ Fp) {
    if (blockIdx.x == 0 && threadIdx.x < 64) {
        int d = threadIdx.x;
        float s = 0.f;
#pragma unroll
        for (int j = 0; j < 64; ++j) s += F[d * 64 + j] * pw[j];
        Fp[d] = s;
    }
    int e = blockIdx.x * blockDim.x + threadIdx.x;
    if (e < Ec) {
        atomicAdd(&deg[un[e]], 1u);
        atomicAdd(&deg[in_[e]], 1u);
    }
}

// --- scan phase 1: per-1024-chunk exclusive scan of deg; also writes dinv ---
__global__ void k_scan1(const unsigned* __restrict__ deg, int* __restrict__ rowptr,
                        int* __restrict__ bsums, float* __restrict__ dinv) {
    __shared__ int sh[256];
    int tid = threadIdx.x, bid = blockIdx.x;
    int base = bid * 1024 + tid * 4;
    int v0 = (base + 0 < Nc) ? (int)deg[base + 0] : 0;
    int v1 = (base + 1 < Nc) ? (int)deg[base + 1] : 0;
    int v2 = (base + 2 < Nc) ? (int)deg[base + 2] : 0;
    int v3 = (base + 3 < Nc) ? (int)deg[base + 3] : 0;
    if (base + 0 < Nc) dinv[base + 0] = v0 ? rsqrtf((float)v0) : 0.f;
    if (base + 1 < Nc) dinv[base + 1] = v1 ? rsqrtf((float)v1) : 0.f;
    if (base + 2 < Nc) dinv[base + 2] = v2 ? rsqrtf((float)v2) : 0.f;
    if (base + 3 < Nc) dinv[base + 3] = v3 ? rsqrtf((float)v3) : 0.f;
    int s = v0 + v1 + v2 + v3;
    sh[tid] = s;
    __syncthreads();
    for (int off = 1; off < 256; off <<= 1) {
        int t = (tid >= off) ? sh[tid - off] : 0;
        __syncthreads();
        sh[tid] += t;
        __syncthreads();
    }
    int excl = sh[tid] - s;
    if (tid == 255) bsums[bid] = sh[255];
    if (base + 0 < Nc) rowptr[base + 0] = excl;
    if (base + 1 < Nc) rowptr[base + 1] = excl + v0;
    if (base + 2 < Nc) rowptr[base + 2] = excl + v0 + v1;
    if (base + 3 < Nc) rowptr[base + 3] = excl + v0 + v1 + v2;
}

// scan of bsums folded in (each block redundantly scans the 147 sums in LDS)
__global__ void k_scan3(int* __restrict__ rowptr, const int* __restrict__ bsums,
                        int* __restrict__ cursor) {
    __shared__ int sh[256];
    int tid = threadIdx.x;
    int v = (tid < NBS) ? bsums[tid] : 0;
    sh[tid] = v;
    __syncthreads();
    for (int off = 1; off < 256; off <<= 1) {
        int t = (tid >= off) ? sh[tid - off] : 0;
        __syncthreads();
        sh[tid] += t;
        __syncthreads();
    }
    int excl = sh[tid] - v;
    __syncthreads();
    sh[tid] = excl;
    __syncthreads();
    int i = blockIdx.x * blockDim.x + threadIdx.x;
    if (i < Nc) {
        int r = rowptr[i] + sh[i >> 10];
        rowptr[i] = r;
        cursor[i] = r;
    }
    if (i == 0) rowptr[Nc] = 2 * Ec;
}

// fused: edge-weight projection + CSR scatter (both directions, same coef)
__global__ void k_build(const int* __restrict__ un, const int* __restrict__ in_,
                        const float* __restrict__ ef, const float* __restrict__ Fp,
                        const float* __restrict__ pb, const float* __restrict__ dinv,
                        int* __restrict__ cursor, int2* __restrict__ csr) {
    int t = blockIdx.x * blockDim.x + threadIdx.x;
    int e = t >> 4, l = t & 15;
    if (e >= Ec) return;
    float4 f = reinterpret_cast<const float4*>(ef)[(size_t)e * 16 + l];
    float4 w = reinterpret_cast<const float4*>(Fp)[l];
    float s = f.x * w.x + f.y * w.y + f.z * w.z + f.w * w.w;
    s += __shfl_xor(s, 8, 16);
    s += __shfl_xor(s, 4, 16);
    s += __shfl_xor(s, 2, 16);
    s += __shfl_xor(s, 1, 16);
    if (l == 0 || l == 8) {
        int uu = un[e], ii = in_[e];
        float c = dinv[uu] * dinv[ii] * (s + pb[0]);
        if (l == 0) {
            int pos = atomicAdd(&cursor[ii], 1);
            csr[pos] = make_int2(uu, __float_as_int(c));
        } else {
            int pos = atomicAdd(&cursor[uu], 1);
            csr[pos] = make_int2(ii, __float_as_int(c));
        }
    }
}

// gather propagation, full graph, 4x ILP-unrolled edge loop (R3-proven config).
// SPLIT=1: layer-1, sources come straight from Gu/Gi (bipartite).
template <int SPLIT>
__global__ void k_gprop(const int* __restrict__ rowptr, const int2* __restrict__ csr,
                        const float* __restrict__ xGu, const float* __restrict__ xGi,
                        float* __restrict__ xn) {
    int t = blockIdx.x * blockDim.x + threadIdx.x;
    int n = t >> 4, l = t & 15;
    if (n >= Nc) return;
    int e0 = rowptr[n], e1 = rowptr[n + 1];
    const float4* xs;
    int off = 0;
    if (SPLIT) {
        if (n < Uc) { xs = reinterpret_cast<const float4*>(xGi); off = Uc * 16; }
        else        { xs = reinterpret_cast<const float4*>(xGu); }
    } else {
        xs = reinterpret_cast<const float4*>(xGu);
    }
    float4 acc = make_float4(0.f, 0.f, 0.f, 0.f);
    int e = e0;
    for (; e + 4 <= e1; e += 4) {
        int2 s0 = csr[e], s1 = csr[e + 1], s2 = csr[e + 2], s3 = csr[e + 3];
        float4 v0 = xs[s0.x * 16 - off + l];
        float4 v1 = xs[s1.x * 16 - off + l];
        float4 v2 = xs[s2.x * 16 - off + l];
        float4 v3 = xs[s3.x * 16 - off + l];
        float c0 = __int_as_float(s0.y), c1 = __int_as_float(s1.y);
        float c2 = __int_as_float(s2.y), c3 = __int_as_float(s3.y);
        acc.x += c0 * v0.x + c1 * v1.x + c2 * v2.x + c3 * v3.x;
        acc.y += c0 * v0.y + c1 * v1.y + c2 * v2.y + c3 * v3.y;
        acc.z += c0 * v0.z + c1 * v1.z + c2 * v2.z + c3 * v3.z;
        acc.w += c0 * v0.w + c1 * v1.w + c2 * v2.w + c3 * v3.w;
    }
    for (; e < e1; ++e) {
        int2 sc = csr[e];
        float c = __int_as_float(sc.y);
        float4 v = xs[sc.x * 16 - off + l];
        acc.x += c * v.x; acc.y += c * v.y; acc.z += c * v.z; acc.w += c * v.w;
    }
    reinterpret_cast<float4*>(xn)[n * 16 + l] = acc;
}

// fused batch-side: acc = x0 + a1 x1 + a2 x2 + a3 (A x2), then dot.
// One 64-lane wave per (user,item) pair; lane = feature dim.
__global__ void k_final(const float* __restrict__ Gu, const float* __restrict__ Gi,
                        const float* __restrict__ x1, const float* __restrict__ x2,
                        const int* __restrict__ rowptr, const int2* __restrict__ csr,
                        const int* __restrict__ users, const int* __restrict__ items,
                        float* __restrict__ out) {
    int wid = (blockIdx.x * blockDim.x + threadIdx.x) >> 6;
    int d = threadIdx.x & 63;
    if (wid >= Bc) return;
    int un = users[wid];
    int in_ = Uc + items[wid];

    float acc2[2];
#pragma unroll
    for (int side = 0; side < 2; ++side) {
        int n = side ? in_ : un;
        float base = side ? Gi[(size_t)(n - Uc) * 64 + d] : Gu[(size_t)n * 64 + d];
        float a = base + 0.5f * x1[(size_t)n * 64 + d] + (1.f / 3.f) * x2[(size_t)n * 64 + d];
        float su = 0.f;
        int e0 = rowptr[n], e1 = rowptr[n + 1];
        int e = e0;
        for (; e + 4 <= e1; e += 4) {
            int2 s0 = csr[e], s1 = csr[e + 1], s2 = csr[e + 2], s3 = csr[e + 3];
            su += __int_as_float(s0.y) * x2[(size_t)s0.x * 64 + d]
                + __int_as_float(s1.y) * x2[(size_t)s1.x * 64 + d]
                + __int_as_float(s2.y) * x2[(size_t)s2.x * 64 + d]
                + __int_as_float(s3.y) * x2[(size_t)s3.x * 64 + d];
        }
        for (; e < e1; ++e) {
            int2 sc = csr[e];
            su += __int_as_float(sc.y) * x2[(size_t)sc.x * 64 + d];
        }
        acc2[side] = a + 0.25f * su;
    }

    float p = acc2[0] * acc2[1];
#pragma unroll
    for (int o = 32; o > 0; o >>= 1) p += __shfl_xor(p, o, 64);
    if (d == 0) out[wid] = p;
}

// ---------------- launch ----------------

extern "C" void kernel_launch(void* const* d_in, const int* in_sizes, int n_in,
                              void* d_out, int out_size, void* d_ws, size_t ws_size,
                              hipStream_t stream) {
    const float* Gu = (const float*)d_in[0];
    const float* Gi = (const float*)d_in[1];
    const float* F  = (const float*)d_in[2];
    const float* pw = (const float*)d_in[3];
    const float* pb = (const float*)d_in[4];
    const float* ef = (const float*)d_in[5];
    const int*   ei = (const int*)d_in[6];   // [2, 2E]
    const int* users = (const int*)d_in[7];
    const int* items = (const int*)d_in[8];
    float* out = (float*)d_out;

    float* ws = (float*)d_ws;
    float*    Fp     = ws;                          // 64
    float*    dinv   = Fp + 64;                     // N
    unsigned* deg    = (unsigned*)(dinv + Nc);      // N
    int*      rowptr = (int*)(deg + Nc);            // N+16
    int*      cursor = rowptr + (Nc + 16);          // N
    int*      bsums  = cursor + Nc;                 // 256
    int2*     csr    = (int2*)(bsums + 256);        // 2E int2
    float*    xa     = (float*)(csr + 2 * Ec);      // N*64
    float*    xb     = xa + (size_t)Nc * 64;        // N*64

    const int* un  = ei;            // user ids (first half of row 0)
    const int* in_ = ei + 2 * Ec;   // item node ids >= U (first half of row 1)

    k_zero<<<(Nc / 4 + 255) / 256, 256, 0, stream>>>((uint4*)deg);
    k_deg2_fproj<<<(Ec + 255) / 256, 256, 0, stream>>>(un, in_, deg, F, pw, Fp);
    k_scan1<<<NBS, 256, 0, stream>>>(deg, rowptr, bsums, dinv);
    k_scan3<<<(Nc + 255) / 256, 256, 0, stream>>>(rowptr, bsums, cursor);
    k_build<<<(Ec * 16) / 256, 256, 0, stream>>>(un, in_, ef, Fp, pb, dinv, cursor, csr);

    // layer 1: inputs -> xa ; layer 2: xa -> xb
    k_gprop<1><<<(Nc * 16 + 255) / 256, 256, 0, stream>>>(rowptr, csr, Gu, Gi, xa);
    k_gprop<0><<<(Nc * 16 + 255) / 256, 256, 0, stream>>>(rowptr, csr, xa, nullptr, xb);

    // fused: alpha-weighted batch accumulation + layer-3 on the fly + dot
    k_final<<<(Bc * 64) / 256, 256, 0, stream>>>(Gu, Gi, xa, xb, rowptr, csr, users, items, out);
}

// Round 7
// 351.816 us; speedup vs baseline: 1.2037x; 1.1289x over previous
//
#include <hip/hip_runtime.h>

constexpr int Uc = 100000;
constexpr int Ic = 50000;
constexpr int Nc = 150000;   // U + I
constexpr int Ec = 1000000;
constexpr int Bc = 16384;
constexpr int NBS = (Nc + 1023) / 1024;  // scan chunks = 147

typedef _Float16 h16;
union H4 { uint2 u; h16 h[4]; };

// ---------------- kernels ----------------

// zero deg (Nc uints = 37500 uint4)
__global__ void k_zero(uint4* __restrict__ deg4) {
    int i = blockIdx.x * blockDim.x + threadIdx.x;
    if (i < Nc / 4) deg4[i] = make_uint4(0u, 0u, 0u, 0u);
}

// deg count over undirected edges + (block 0) Fp[d] = F[d,:] @ pw
__global__ void k_deg2_fproj(const int* __restrict__ un, const int* __restrict__ in_,
                             unsigned* __restrict__ deg,
                             const float* __restrict__ F, const float* __restrict__ pw,
                             float* __restrict__ Fp) {
    if (blockIdx.x == 0 && threadIdx.x < 64) {
        int d = threadIdx.x;
        float s = 0.f;
#pragma unroll
        for (int j = 0; j < 64; ++j) s += F[d * 64 + j] * pw[j];
        Fp[d] = s;
    }
    int e = blockIdx.x * blockDim.x + threadIdx.x;
    if (e < Ec) {
        atomicAdd(&deg[un[e]], 1u);
        atomicAdd(&deg[in_[e]], 1u);
    }
}

// --- scan phase 1: per-1024-chunk exclusive scan of deg; also writes dinv ---
__global__ void k_scan1(const unsigned* __restrict__ deg, int* __restrict__ rowptr,
                        int* __restrict__ bsums, float* __restrict__ dinv) {
    __shared__ int sh[256];
    int tid = threadIdx.x, bid = blockIdx.x;
    int base = bid * 1024 + tid * 4;
    int v0 = (base + 0 < Nc) ? (int)deg[base + 0] : 0;
    int v1 = (base + 1 < Nc) ? (int)deg[base + 1] : 0;
    int v2 = (base + 2 < Nc) ? (int)deg[base + 2] : 0;
    int v3 = (base + 3 < Nc) ? (int)deg[base + 3] : 0;
    if (base + 0 < Nc) dinv[base + 0] = v0 ? rsqrtf((float)v0) : 0.f;
    if (base + 1 < Nc) dinv[base + 1] = v1 ? rsqrtf((float)v1) : 0.f;
    if (base + 2 < Nc) dinv[base + 2] = v2 ? rsqrtf((float)v2) : 0.f;
    if (base + 3 < Nc) dinv[base + 3] = v3 ? rsqrtf((float)v3) : 0.f;
    int s = v0 + v1 + v2 + v3;
    sh[tid] = s;
    __syncthreads();
    for (int off = 1; off < 256; off <<= 1) {
        int t = (tid >= off) ? sh[tid - off] : 0;
        __syncthreads();
        sh[tid] += t;
        __syncthreads();
    }
    int excl = sh[tid] - s;
    if (tid == 255) bsums[bid] = sh[255];
    if (base + 0 < Nc) rowptr[base + 0] = excl;
    if (base + 1 < Nc) rowptr[base + 1] = excl + v0;
    if (base + 2 < Nc) rowptr[base + 2] = excl + v0 + v1;
    if (base + 3 < Nc) rowptr[base + 3] = excl + v0 + v1 + v2;
}

// bsums scan folded in (each block redundantly scans the 147 sums in LDS)
__global__ void k_scan3(int* __restrict__ rowptr, const int* __restrict__ bsums,
                        int* __restrict__ cursor) {
    __shared__ int sh[256];
    int tid = threadIdx.x;
    int v = (tid < NBS) ? bsums[tid] : 0;
    sh[tid] = v;
    __syncthreads();
    for (int off = 1; off < 256; off <<= 1) {
        int t = (tid >= off) ? sh[tid - off] : 0;
        __syncthreads();
        sh[tid] += t;
        __syncthreads();
    }
    int excl = sh[tid] - v;
    __syncthreads();
    sh[tid] = excl;
    __syncthreads();
    int i = blockIdx.x * blockDim.x + threadIdx.x;
    if (i < Nc) {
        int r = rowptr[i] + sh[i >> 10];
        rowptr[i] = r;
        cursor[i] = r;
    }
    if (i == 0) rowptr[Nc] = 2 * Ec;
}

// fused: edge-weight projection + CSR scatter (both directions, same coef)
__global__ void k_build(const int* __restrict__ un, const int* __restrict__ in_,
                        const float* __restrict__ ef, const float* __restrict__ Fp,
                        const float* __restrict__ pb, const float* __restrict__ dinv,
                        int* __restrict__ cursor, int2* __restrict__ csr) {
    int t = blockIdx.x * blockDim.x + threadIdx.x;
    int e = t >> 4, l = t & 15;
    if (e >= Ec) return;
    float4 f = reinterpret_cast<const float4*>(ef)[(size_t)e * 16 + l];
    float4 w = reinterpret_cast<const float4*>(Fp)[l];
    float s = f.x * w.x + f.y * w.y + f.z * w.z + f.w * w.w;
    s += __shfl_xor(s, 8, 16);
    s += __shfl_xor(s, 4, 16);
    s += __shfl_xor(s, 2, 16);
    s += __shfl_xor(s, 1, 16);
    if (l == 0 || l == 8) {
        int uu = un[e], ii = in_[e];
        float c = dinv[uu] * dinv[ii] * (s + pb[0]);
        if (l == 0) {
            int pos = atomicAdd(&cursor[ii], 1);
            csr[pos] = make_int2(uu, __float_as_int(c));
        } else {
            int pos = atomicAdd(&cursor[uu], 1);
            csr[pos] = make_int2(ii, __float_as_int(c));
        }
    }
}

// convert concat(Gu,Gi) f32 -> xin fp16
__global__ void k_xin(const float* __restrict__ Gu, const float* __restrict__ Gi,
                      uint2* __restrict__ xin) {
    int t = blockIdx.x * blockDim.x + threadIdx.x;  // over Nc*16 groups of 4
    if (t >= Nc * 16) return;
    float4 v = (t < Uc * 16) ? reinterpret_cast<const float4*>(Gu)[t]
                             : reinterpret_cast<const float4*>(Gi)[t - Uc * 16];
    H4 o;
    o.h[0] = (h16)v.x; o.h[1] = (h16)v.y; o.h[2] = (h16)v.z; o.h[3] = (h16)v.w;
    xin[t] = o.u;
}

// gather propagation over fp16 rows (128 B), 4x ILP, f32 accumulate.
__global__ void k_gprop(const int* __restrict__ rowptr, const int2* __restrict__ csr,
                        const uint2* __restrict__ x, uint2* __restrict__ xn) {
    int t = blockIdx.x * blockDim.x + threadIdx.x;
    int n = t >> 4, l = t & 15;
    if (n >= Nc) return;
    int e0 = rowptr[n], e1 = rowptr[n + 1];
    float4 acc = make_float4(0.f, 0.f, 0.f, 0.f);
    int e = e0;
    for (; e + 4 <= e1; e += 4) {
        int2 s0 = csr[e], s1 = csr[e + 1], s2 = csr[e + 2], s3 = csr[e + 3];
        H4 v0, v1, v2, v3;
        v0.u = x[s0.x * 16 + l];
        v1.u = x[s1.x * 16 + l];
        v2.u = x[s2.x * 16 + l];
        v3.u = x[s3.x * 16 + l];
        float c0 = __int_as_float(s0.y), c1 = __int_as_float(s1.y);
        float c2 = __int_as_float(s2.y), c3 = __int_as_float(s3.y);
        acc.x += c0 * (float)v0.h[0] + c1 * (float)v1.h[0] + c2 * (float)v2.h[0] + c3 * (float)v3.h[0];
        acc.y += c0 * (float)v0.h[1] + c1 * (float)v1.h[1] + c2 * (float)v2.h[1] + c3 * (float)v3.h[1];
        acc.z += c0 * (float)v0.h[2] + c1 * (float)v1.h[2] + c2 * (float)v2.h[2] + c3 * (float)v3.h[2];
        acc.w += c0 * (float)v0.h[3] + c1 * (float)v1.h[3] + c2 * (float)v2.h[3] + c3 * (float)v3.h[3];
    }
    for (; e < e1; ++e) {
        int2 sc = csr[e];
        float c = __int_as_float(sc.y);
        H4 v; v.u = x[sc.x * 16 + l];
        acc.x += c * (float)v.h[0]; acc.y += c * (float)v.h[1];
        acc.z += c * (float)v.h[2]; acc.w += c * (float)v.h[3];
    }
    H4 o;
    o.h[0] = (h16)acc.x; o.h[1] = (h16)acc.y; o.h[2] = (h16)acc.z; o.h[3] = (h16)acc.w;
    xn[n * 16 + l] = o.u;
}

// fused batch-side: acc = x0 + a1 x1 + a2 x2 + a3 (A x2), then dot.
// One 64-lane wave per (user,item) pair; lane = feature dim.
__global__ void k_final(const float* __restrict__ Gu, const float* __restrict__ Gi,
                        const h16* __restrict__ x1, const h16* __restrict__ x2,
                        const int* __restrict__ rowptr, const int2* __restrict__ csr,
                        const int* __restrict__ users, const int* __restrict__ items,
                        float* __restrict__ out) {
    int wid = (blockIdx.x * blockDim.x + threadIdx.x) >> 6;
    int d = threadIdx.x & 63;
    if (wid >= Bc) return;
    int un = users[wid];
    int in_ = Uc + items[wid];

    float acc2[2];
#pragma unroll
    for (int side = 0; side < 2; ++side) {
        int n = side ? in_ : un;
        float base = side ? Gi[(size_t)(n - Uc) * 64 + d] : Gu[(size_t)n * 64 + d];
        float a = base + 0.5f * (float)x1[(size_t)n * 64 + d]
                       + (1.f / 3.f) * (float)x2[(size_t)n * 64 + d];
        float su = 0.f;
        int e0 = rowptr[n], e1 = rowptr[n + 1];
        int e = e0;
        for (; e + 4 <= e1; e += 4) {
            int2 s0 = csr[e], s1 = csr[e + 1], s2 = csr[e + 2], s3 = csr[e + 3];
            su += __int_as_float(s0.y) * (float)x2[(size_t)s0.x * 64 + d]
                + __int_as_float(s1.y) * (float)x2[(size_t)s1.x * 64 + d]
                + __int_as_float(s2.y) * (float)x2[(size_t)s2.x * 64 + d]
                + __int_as_float(s3.y) * (float)x2[(size_t)s3.x * 64 + d];
        }
        for (; e < e1; ++e) {
            int2 sc = csr[e];
            su += __int_as_float(sc.y) * (float)x2[(size_t)sc.x * 64 + d];
        }
        acc2[side] = a + 0.25f * su;
    }

    float p = acc2[0] * acc2[1];
#pragma unroll
    for (int o = 32; o > 0; o >>= 1) p += __shfl_xor(p, o, 64);
    if (d == 0) out[wid] = p;
}

// ---------------- launch ----------------

extern "C" void kernel_launch(void* const* d_in, const int* in_sizes, int n_in,
                              void* d_out, int out_size, void* d_ws, size_t ws_size,
                              hipStream_t stream) {
    const float* Gu = (const float*)d_in[0];
    const float* Gi = (const float*)d_in[1];
    const float* F  = (const float*)d_in[2];
    const float* pw = (const float*)d_in[3];
    const float* pb = (const float*)d_in[4];
    const float* ef = (const float*)d_in[5];
    const int*   ei = (const int*)d_in[6];   // [2, 2E]
    const int* users = (const int*)d_in[7];
    const int* items = (const int*)d_in[8];
    float* out = (float*)d_out;

    float* ws = (float*)d_ws;
    float*    Fp     = ws;                          // 64
    float*    dinv   = Fp + 64;                     // N
    unsigned* deg    = (unsigned*)(dinv + Nc);      // N
    int*      rowptr = (int*)(deg + Nc);            // N+16
    int*      cursor = rowptr + (Nc + 16);          // N
    int*      bsums  = cursor + Nc;                 // 256
    int2*     csr    = (int2*)(bsums + 256);        // 2E int2 (16 MB)
    h16*      xin    = (h16*)(csr + 2 * Ec);        // N*64 fp16 (19.2 MB)
    h16*      xa     = xin + (size_t)Nc * 64;       // N*64 fp16
    h16*      xb     = xa + (size_t)Nc * 64;        // N*64 fp16

    const int* un  = ei;            // user ids (first half of row 0)
    const int* in_ = ei + 2 * Ec;   // item node ids >= U (first half of row 1)

    k_zero<<<(Nc / 4 + 255) / 256, 256, 0, stream>>>((uint4*)deg);
    k_deg2_fproj<<<(Ec + 255) / 256, 256, 0, stream>>>(un, in_, deg, F, pw, Fp);
    k_scan1<<<NBS, 256, 0, stream>>>(deg, rowptr, bsums, dinv);
    k_scan3<<<(Nc + 255) / 256, 256, 0, stream>>>(rowptr, bsums, cursor);
    k_build<<<(Ec * 16) / 256, 256, 0, stream>>>(un, in_, ef, Fp, pb, dinv, cursor, csr);
    k_xin<<<(Nc * 16 + 255) / 256, 256, 0, stream>>>(Gu, Gi, (uint2*)xin);

    // layer 1: xin -> xa ; layer 2: xa -> xb   (fp16 rows, unified node index)
    k_gprop<<<(Nc * 16 + 255) / 256, 256, 0, stream>>>(rowptr, csr, (const uint2*)xin, (uint2*)xa);
    k_gprop<<<(Nc * 16 + 255) / 256, 256, 0, stream>>>(rowptr, csr, (const uint2*)xa, (uint2*)xb);

    // fused: alpha-weighted batch accumulation + layer-3 on the fly + dot
    k_final<<<(Bc * 64) / 256, 256, 0, stream>>>(Gu, Gi, xa, xb, rowptr, csr, users, items, out);
}